// Round 6
// baseline (323.256 us; speedup 1.0000x reference)
//
#include <hip/hip_runtime.h>
#include <hip/hip_cooperative_groups.h>
#include <cstdint>
#include <cstddef>

namespace cg = cooperative_groups;
typedef unsigned long long u64;

// ---------------- problem constants ----------------
constexpr int Bn   = 8;
constexpr int Pn   = 2000;
constexpr int Cn   = 81;
constexpr int CM1  = 80;
constexpr int Mn   = Pn * CM1;      // 160000 per image
constexpr int KPRE = 2048;
constexpr int NDET = 100;
constexpr int NSEC = 16;            // sections per image
constexpr int SPROP = Pn / NSEC;    // 125 proposals per section
constexpr int CBUFN = 4096;         // LDS key buffer (max valid/section = 125*19 = 2375)
constexpr float W_IMG = 1333.0f;
constexpr float H_IMG = 800.0f;
constexpr float XFORM_CLIP = 4.135166556742356f; // log(1000/16)
constexpr float NMS_OFF = 1334.0f;               // max(W,H)+1

// ---------------- ws layout (bytes); everything written before read ----------
constexpr size_t OFF_LA  = 0;                                  // 128*KPRE u64 (2 MB)
constexpr size_t OFF_LB  = OFF_LA + (size_t)128 * KPRE * 8;    // 64*KPRE u64 (1 MB)
constexpr size_t OFF_LC  = OFF_LB + (size_t)64 * KPRE * 8;     // 32*KPRE u64
constexpr size_t OFF_LD  = OFF_LC + (size_t)32 * KPRE * 8;     // 16*KPRE u64
constexpr size_t OFF_C0  = OFF_LD + (size_t)16 * KPRE * 8;     // 128 int
constexpr size_t OFF_C1  = OFF_C0 + 128 * 4;                   // 64 int
constexpr size_t OFF_C2  = OFF_C1 + 64 * 4;                    // 32 int
constexpr size_t OFF_C3  = OFF_C2 + 32 * 4;                    // 16 int

__device__ __forceinline__ void decode_clip(const float4 rv, float w, float h,
                                            float cx, float cy, float out[4]) {
  float dx = rv.x / 10.0f;
  float dy = rv.y / 10.0f;
  float dw = fminf(rv.z / 5.0f, XFORM_CLIP);
  float dh = fminf(rv.w / 5.0f, XFORM_CLIP);
  float pcx = dx * w + cx;
  float pcy = dy * h + cy;
  float pw = expf(dw) * w;
  float ph = expf(dh) * h;
  out[0] = fminf(fmaxf(pcx - 0.5f * pw, 0.0f), W_IMG);
  out[1] = fminf(fmaxf(pcy - 0.5f * ph, 0.0f), H_IMG);
  out[2] = fminf(fmaxf(pcx + 0.5f * pw, 0.0f), W_IMG);
  out[3] = fminf(fmaxf(pcy + 0.5f * ph, 0.0f), H_IMG);
}

// decode a candidate key into raw clipped box + label + score
__device__ __forceinline__ void key_decode(u64 key, int b,
                                           const float* __restrict__ reg,
                                           const float* __restrict__ props,
                                           float bx[4], int& label, float& sc) {
  sc = __uint_as_float((unsigned)(key >> 32));
  bx[0] = bx[1] = bx[2] = bx[3] = 0.0f;
  label = 0;
  if (key != 0ull) {
    int m = (int)(0xFFFFFFFFu - (unsigned)key);
    int p = m / CM1;
    int c = m - p * CM1 + 1;
    int nidx = b * Pn + p;
    const float4 pb = *reinterpret_cast<const float4*>(props + (size_t)nidx * 4);
    float w = pb.z - pb.x, h = pb.w - pb.y;
    float cx = pb.x + 0.5f * w, cy = pb.y + 0.5f * h;
    float4 rv = *reinterpret_cast<const float4*>(reg + (size_t)nidx * (Cn * 4) + c * 4);
    decode_clip(rv, w, h, cx, cy, bx);
    label = c;
  }
}

// staged merge-path merge of two sorted-desc lists (LDS stage <= 4096 keys)
__device__ __forceinline__ void merge_staged(const u64* __restrict__ A, int nA,
                                             const u64* __restrict__ B, int nB,
                                             u64* __restrict__ dst, u64* stage, int t) {
  for (int i = t; i < nA; i += 256) stage[i] = A[i];
  for (int i = t; i < nB; i += 256) stage[nA + i] = B[i];
  __syncthreads();
  int outLen = min(nA + nB, KPRE);
  const u64* sA = stage;
  const u64* sB = stage + nA;
  int CH = (outLen + 255) >> 8;  // <= 8
  int d = t * CH;
  if (d < outLen) {
    int lo = max(0, d - nB), hi = min(d, nA);
    while (lo < hi) {
      int mid = (lo + hi) >> 1;
      if (sA[mid] >= sB[d - 1 - mid]) lo = mid + 1; else hi = mid;
    }
    int i = lo, j = d - lo;
    int e_end = min(CH, outLen - d);
    for (int e = 0; e < e_end; e++) {
      u64 v;
      if (j >= nB || (i < nA && sA[i] >= sB[j])) v = sA[i++];
      else v = sB[j++];
      dst[d + e] = v;
    }
  }
  __syncthreads();
}

// ---------------- the single cooperative mega-kernel ----------------
__global__ __launch_bounds__(256) void
mega_kernel(const float* __restrict__ logits, const float* __restrict__ reg,
            const float* __restrict__ props, float* __restrict__ out,
            u64* __restrict__ LA, u64* __restrict__ LB, u64* __restrict__ LC,
            u64* __restrict__ LDl, int* __restrict__ cnt0, int* __restrict__ cnt1,
            int* __restrict__ cnt2, int* __restrict__ cnt3) {
  cg::grid_group grid = cg::this_grid();
  int blk = blockIdx.x, t = threadIdx.x, lane = t & 63, wv = t >> 6;

  __shared__ __align__(16) char smem[57344];
  u64* cbuf = (u64*)smem;                         // 4096 keys (phases 1-3)
  u64* accK = (u64*)smem;                         // 2048 keys (phase 4+)
  float4* obox = (float4*)(smem + 16384);         // 2048 boxes (NMS)
  u64 (*maskb)[4] = (u64 (*)[4])(smem + 49152);   // 8 KB
  __shared__ u64 keepw[KPRE / 64];
  __shared__ int accI[NDET];
  __shared__ int kcnt_sh;
  __shared__ int cnt_sh;

  // ================= phase 1: score+decode+compact own section ==============
  {
    int b = blk >> 4, s = blk & 15;
    if (t == 0) cnt_sh = 0;
    __syncthreads();
    int p0 = s * SPROP;
    for (int pp = wv; pp < SPROP; pp += 4) {
      int p = p0 + pp;
      int wid = b * Pn + p;
      const float* lg = logits + (size_t)wid * Cn;
      float x0 = lg[lane];
      float x1 = (lane < Cn - 64) ? lg[64 + lane] : -3.4e38f;
      float mx = fmaxf(x0, x1);
      for (int m = 32; m; m >>= 1) mx = fmaxf(mx, __shfl_xor(mx, m, 64));
      float e0 = expf(x0 - mx);
      float e1 = (lane < Cn - 64) ? expf(x1 - mx) : 0.0f;
      float ssum = e0 + e1;
      for (int m = 32; m; m >>= 1) ssum += __shfl_xor(ssum, m, 64);

      const float4 pb = *reinterpret_cast<const float4*>(props + (size_t)wid * 4);
      float w = pb.z - pb.x, h = pb.w - pb.y;
      float cx = pb.x + 0.5f * w, cy = pb.y + 0.5f * h;
      const float* rrow = reg + (size_t)wid * (Cn * 4);

      u64 key0 = 0ull, key1 = 0ull;
      if (lane >= 1) {  // class c = lane (1..63)
        float sc = e0 / ssum;
        float4 rv = *reinterpret_cast<const float4*>(rrow + lane * 4);
        float bx[4];
        decode_clip(rv, w, h, cx, cy, bx);
        if ((sc > 0.05f) && (bx[2] - bx[0] >= 0.01f) && (bx[3] - bx[1] >= 0.01f)) {
          unsigned m = (unsigned)(p * CM1 + (lane - 1));
          key0 = ((u64)__float_as_uint(sc) << 32) | (0xFFFFFFFFu - m);
        }
      }
      if (lane < Cn - 64) {  // class c = 64+lane (64..80)
        int c = 64 + lane;
        float sc = e1 / ssum;
        float4 rv = *reinterpret_cast<const float4*>(rrow + c * 4);
        float bx[4];
        decode_clip(rv, w, h, cx, cy, bx);
        if ((sc > 0.05f) && (bx[2] - bx[0] >= 0.01f) && (bx[3] - bx[1] >= 0.01f)) {
          unsigned m = (unsigned)(p * CM1 + (c - 1));
          key1 = ((u64)__float_as_uint(sc) << 32) | (0xFFFFFFFFu - m);
        }
      }
      u64 bal0 = __ballot(key0 != 0ull);
      u64 bal1 = __ballot(key1 != 0ull);
      int tot = __popcll(bal0) + __popcll(bal1);
      int base = 0;
      if (lane == 0 && tot) base = atomicAdd(&cnt_sh, tot);
      base = __shfl(base, 0, 64);
      int r0 = __popcll(bal0 & ((1ull << lane) - 1ull));
      int r1 = __popcll(bal0) + __popcll(bal1 & ((1ull << lane) - 1ull));
      if (key0) cbuf[base + r0] = key0;
      if (key1) cbuf[base + r1] = key1;
    }
    __syncthreads();

    // ============== phase 2: bitonic sort section candidates ===============
    int n = cnt_sh;  // <= 2375
    int npow = 2;
    while (npow < n) npow <<= 1;
    for (int i = n + t; i < npow; i += 256) cbuf[i] = 0ull;
    __syncthreads();
    for (int k = 2; k <= npow; k <<= 1) {
      for (int j = k >> 1; j > 0; j >>= 1) {
        for (int i = t; i < npow; i += 256) {
          int ixj = i ^ j;
          if (ixj > i) {
            u64 a = cbuf[i], c2 = cbuf[ixj];
            bool dir = ((i & k) == 0);  // descending overall
            if ((a < c2) == dir) { cbuf[i] = c2; cbuf[ixj] = a; }
          }
        }
        __syncthreads();
      }
    }
    int outn = min(n, KPRE);
    u64* dst = LA + (size_t)blk * KPRE;
    for (int i = t; i < outn; i += 256) dst[i] = cbuf[i];
    if (t == 0) cnt0[blk] = outn;
  }
  __threadfence();
  grid.sync();

  // ================= merge level 1: 16 -> 8 lists per image =================
  if (blk < 64) {
    int img = blk >> 3, pr = blk & 7;
    int ia = img * 16 + 2 * pr;
    int nA = cnt0[ia], nB = cnt0[ia + 1];
    merge_staged(LA + (size_t)ia * KPRE, nA, LA + (size_t)(ia + 1) * KPRE, nB,
                 LB + (size_t)(img * 8 + pr) * KPRE, cbuf, t);
    if (t == 0) cnt1[img * 8 + pr] = min(nA + nB, KPRE);
  }
  __threadfence();
  grid.sync();

  // ================= merge level 2: 8 -> 4 =================================
  if (blk < 32) {
    int img = blk >> 2, pr = blk & 3;
    int ia = img * 8 + 2 * pr;
    int nA = cnt1[ia], nB = cnt1[ia + 1];
    merge_staged(LB + (size_t)ia * KPRE, nA, LB + (size_t)(ia + 1) * KPRE, nB,
                 LC + (size_t)(img * 4 + pr) * KPRE, cbuf, t);
    if (t == 0) cnt2[img * 4 + pr] = min(nA + nB, KPRE);
  }
  __threadfence();
  grid.sync();

  // ================= merge level 3: 4 -> 2 =================================
  if (blk < 16) {
    int img = blk >> 1, pr = blk & 1;
    int ia = img * 4 + 2 * pr;
    int nA = cnt2[ia], nB = cnt2[ia + 1];
    merge_staged(LC + (size_t)ia * KPRE, nA, LC + (size_t)(ia + 1) * KPRE, nB,
                 LDl + (size_t)(img * 2 + pr) * KPRE, cbuf, t);
    if (t == 0) cnt3[img * 2 + pr] = min(nA + nB, KPRE);
  }
  __threadfence();
  grid.sync();

  // ================= final: merge 2 -> top-2048 + NMS (8 blocks) ============
  if (blk >= Bn) return;
  int img = blk;
  int w = t >> 6;
  {
    int nA = cnt3[2 * img], nB = cnt3[2 * img + 1];
    const u64* A = LDl + (size_t)(2 * img) * KPRE;
    const u64* B = LDl + (size_t)(2 * img + 1) * KPRE;
    int outLen = min(nA + nB, KPRE);
    int d = t * 8;
    if (d < outLen) {
      int lo = max(0, d - nB), hi = min(d, nA);
      while (lo < hi) {
        int mid = (lo + hi) >> 1;
        if (A[mid] >= B[d - 1 - mid]) lo = mid + 1; else hi = mid;
      }
      int i = lo, j = d - lo;
      int e_end = min(8, outLen - d);
      for (int e = 0; e < e_end; e++) {
        u64 v;
        if (j >= nB || (i < nA && A[i] >= B[j])) v = A[i++];
        else v = B[j++];
        accK[d + e] = v;
      }
    }
    for (int i2 = outLen + t; i2 < KPRE; i2 += 256) accK[i2] = 0ull;
  }
  __syncthreads();

  // ---- decode boxes into LDS ----
  #pragma unroll
  for (int s = 0; s < 8; s++) {
    int j = t + s * 256;
    u64 key = accK[j];
    float bx[4]; int label; float sc;
    key_decode(key, img, reg, props, bx, label, sc);
    float off = (float)label * NMS_OFF;
    obox[j] = make_float4(bx[0] + off, bx[1] + off, bx[2] + off, bx[3] + off);
    u64 bal = __ballot(key != 0ull);
    if (lane == 0) keepw[s * 4 + w] = bal;
  }
  __syncthreads();

  // ---- windowed bitmask greedy NMS with early exit ----
  int kcount = 0;
  for (int w0 = 0; w0 < KPRE && kcount < NDET; w0 += 256) {
    if (w0 > 0 && kcount > 0) {
      int j = w0 + t;
      u64 kwv = keepw[j >> 6];
      bool alive = (kwv >> (j & 63)) & 1ull;
      if (alive) {
        float4 jb = obox[j];
        float jar = fmaxf(jb.z - jb.x, 0.0f) * fmaxf(jb.w - jb.y, 0.0f);
        for (int a = 0; a < kcount; a++) {
          float4 ab = obox[accI[a]];
          float ix1 = fmaxf(ab.x, jb.x), iy1 = fmaxf(ab.y, jb.y);
          float ix2 = fminf(ab.z, jb.z), iy2 = fminf(ab.w, jb.w);
          float iw = fmaxf(ix2 - ix1, 0.0f), ih = fmaxf(iy2 - iy1, 0.0f);
          float inter = iw * ih;
          if (inter > 0.0f) {
            float aar = fmaxf(ab.z - ab.x, 0.0f) * fmaxf(ab.w - ab.y, 0.0f);
            float iou = inter / fmaxf(aar + jar - inter, 1e-9f);
            if (iou > 0.5f) { alive = false; break; }
          }
        }
      }
      u64 bal = __ballot(alive);
      if (lane == 0) keepw[(w0 >> 6) + w] = bal;
      __syncthreads();
    }
    // window-internal suppression bitmask (thread t = row t)
    {
      int rgp = w0 + t;
      bool ralive = (keepw[rgp >> 6] >> (rgp & 63)) & 1ull;
      float4 rb = obox[rgp];
      float rar = fmaxf(rb.z - rb.x, 0.0f) * fmaxf(rb.w - rb.y, 0.0f);
      #pragma unroll
      for (int wd = 0; wd < 4; wd++) {
        u64 m = 0;
        if (ralive) {
          int cb0 = w0 + wd * 64;
          for (int jj = 0; jj < 64; jj++) {
            int cg = cb0 + jj;
            float4 cb = obox[cg];
            float ix1 = fmaxf(rb.x, cb.x), iy1 = fmaxf(rb.y, cb.y);
            float ix2 = fminf(rb.z, cb.z), iy2 = fminf(rb.w, cb.w);
            float iw = fmaxf(ix2 - ix1, 0.0f), ih = fmaxf(iy2 - iy1, 0.0f);
            float inter = iw * ih;
            if (inter > 0.0f && cg > rgp) {
              float car = fmaxf(cb.z - cb.x, 0.0f) * fmaxf(cb.w - cb.y, 0.0f);
              float iou = inter / fmaxf(rar + car - inter, 1e-9f);
              if (iou > 0.5f) m |= (1ull << jj);
            }
          }
        }
        maskb[t][wd] = m;
      }
    }
    __syncthreads();
    // single-wave serial greedy reduce over the window
    if (w == 0) {
      u64 kw0 = keepw[(w0 >> 6) + 0];
      u64 kw1 = keepw[(w0 >> 6) + 1];
      u64 kw2 = keepw[(w0 >> 6) + 2];
      u64 kw3 = keepw[(w0 >> 6) + 3];
      int kc = kcount;
      #pragma unroll
      for (int wq = 0; wq < 4; wq++) {
        u64 cw = (wq == 0) ? kw0 : (wq == 1) ? kw1 : (wq == 2) ? kw2 : kw3;
        if (cw == 0ull) continue;
        for (int rb0 = 0; rb0 < 64 && kc < NDET; rb0 += 4) {
          u64 gbits = (cw >> rb0) & 0xFull;
          int r = wq * 64 + rb0;
          u64 rm0a = maskb[r][0],   rm0b = maskb[r][1],   rm0c = maskb[r][2],   rm0d = maskb[r][3];
          u64 rm1a = maskb[r+1][0], rm1b = maskb[r+1][1], rm1c = maskb[r+1][2], rm1d = maskb[r+1][3];
          u64 rm2a = maskb[r+2][0], rm2b = maskb[r+2][1], rm2c = maskb[r+2][2], rm2d = maskb[r+2][3];
          u64 rm3a = maskb[r+3][0], rm3b = maskb[r+3][1], rm3c = maskb[r+3][2], rm3d = maskb[r+3][3];
          if (gbits == 0ull) continue;
          #pragma unroll
          for (int d = 0; d < 4; d++) {
            u64 cwq = (wq == 0) ? kw0 : (wq == 1) ? kw1 : (wq == 2) ? kw2 : kw3;
            if ((cwq >> (rb0 + d)) & 1ull) {
              if (lane == 0) accI[kc] = w0 + r + d;
              kc++;
              if (kc >= NDET) break;
              u64 ma = (d == 0) ? rm0a : (d == 1) ? rm1a : (d == 2) ? rm2a : rm3a;
              u64 mb = (d == 0) ? rm0b : (d == 1) ? rm1b : (d == 2) ? rm2b : rm3b;
              u64 mc = (d == 0) ? rm0c : (d == 1) ? rm1c : (d == 2) ? rm2c : rm3c;
              u64 md = (d == 0) ? rm0d : (d == 1) ? rm1d : (d == 2) ? rm2d : rm3d;
              kw0 &= ~ma; kw1 &= ~mb; kw2 &= ~mc; kw3 &= ~md;
            }
          }
          cw = (wq == 0) ? kw0 : (wq == 1) ? kw1 : (wq == 2) ? kw2 : kw3;
        }
      }
      if (lane == 0) {
        keepw[(w0 >> 6) + 0] = kw0;
        keepw[(w0 >> 6) + 1] = kw1;
        keepw[(w0 >> 6) + 2] = kw2;
        keepw[(w0 >> 6) + 3] = kw3;
        kcnt_sh = kc;
      }
    }
    __syncthreads();
    kcount = kcnt_sh;
  }

  // rare path: fewer than 100 kept -> backfill non-kept ascending
  if (t == 0 && kcount < NDET) {
    int run = kcount;
    for (int wq = 0; wq < KPRE / 64 && run < NDET; wq++) {
      u64 nk = ~keepw[wq];
      while (nk && run < NDET) {
        int bit2 = __ffsll((long long)nk) - 1;
        nk &= nk - 1;
        accI[run++] = wq * 64 + bit2;
      }
    }
  }
  __syncthreads();

  if (t < NDET) {
    int k = accI[t];
    bool kept = t < kcount;
    u64 key = accK[k];
    float bx[4]; int label; float sc;
    key_decode(key, img, reg, props, bx, label, sc);
    int oi = img * NDET + t;
    out[(size_t)oi * 4 + 0] = bx[0];
    out[(size_t)oi * 4 + 1] = bx[1];
    out[(size_t)oi * 4 + 2] = bx[2];
    out[(size_t)oi * 4 + 3] = bx[3];
    out[Bn * NDET * 4 + oi] = kept ? sc : -1.0f;
    out[Bn * NDET * 5 + oi] = (float)label;
    out[Bn * NDET * 6 + oi] = kept ? 1.0f : 0.0f;
  }
}

extern "C" void kernel_launch(void* const* d_in, const int* in_sizes, int n_in,
                              void* d_out, int out_size, void* d_ws, size_t ws_size,
                              hipStream_t stream) {
  const float* logits = (const float*)d_in[0];
  const float* reg    = (const float*)d_in[1];
  const float* props  = (const float*)d_in[2];
  float* out = (float*)d_out;
  char* ws = (char*)d_ws;

  u64* LA  = (u64*)(ws + OFF_LA);
  u64* LB  = (u64*)(ws + OFF_LB);
  u64* LC  = (u64*)(ws + OFF_LC);
  u64* LDl = (u64*)(ws + OFF_LD);
  int* cnt0 = (int*)(ws + OFF_C0);
  int* cnt1 = (int*)(ws + OFF_C1);
  int* cnt2 = (int*)(ws + OFF_C2);
  int* cnt3 = (int*)(ws + OFF_C3);

  void* args[] = {&logits, &reg, &props, &out, &LA, &LB, &LC, &LDl,
                  &cnt0, &cnt1, &cnt2, &cnt3};
  hipLaunchCooperativeKernel((const void*)mega_kernel, dim3(128), dim3(256),
                             args, 0, stream);
}